// Round 3
// baseline (113.272 us; speedup 1.0000x reference)
//
#include <hip/hip_runtime.h>
#include <hip/hip_bf16.h>

typedef __hip_bfloat16 bf16;
typedef short bf16x8 __attribute__((ext_vector_type(8)));
typedef float f32x4 __attribute__((ext_vector_type(4)));

#define S_LEN 4096
#define NBATCH 2
#define EDIM 1024
#define DDIM 64
#define MROWS (NBATCH * S_LEN)   // 8192

union frag_u { bf16x8 v; bf16 e[8]; };

// f32x8 -> split bf16 hi/lo fragments (x ~= hi + lo, rel err ~2^-17)
__device__ __forceinline__ void cvt_split(const float4& a, const float4& b,
                                          bf16x8& hi, bf16x8& lo) {
  float v[8] = {a.x, a.y, a.z, a.w, b.x, b.y, b.z, b.w};
  frag_u h, l;
#pragma unroll
  for (int e = 0; e < 8; e++) {
    bf16 hh = __float2bfloat16(v[e]);
    h.e[e] = hh;
    l.e[e] = __float2bfloat16(v[e] - __bfloat162float(hh));
  }
  hi = h.v;
  lo = l.v;
}

// ---------------------------------------------------------------------------
// Pack weights (f32, k-major [1024][64]) -> split-bf16 in ROUND-MAJOR
// order: Wt2[j=0..31][unit u=0..767][8 bf16], round j covers k in
// [j*32, j*32+32). Unit for (n, kk): n2 = n>>1, pp = (n&1)*4 + (kk>>3),
// sp = pp ^ (n2 & 7), u = n2*8 + sp, elem = kk&7. A round block = 12288 B.
// The gemm reads lane units DIRECTLY from global (each (nt, round) is a
// contiguous, fully-consumed 1 KB segment -> perfect coalescing, L2-hot).
// Grid 48 = 3 mats x 16 k-blocks. Block 0 zeroes Vsum.
// ---------------------------------------------------------------------------
__global__ __launch_bounds__(256) void pack_w_kernel(
    const float* __restrict__ Wq, const float* __restrict__ Wk,
    const float* __restrict__ Wv, bf16* __restrict__ Wt2_hi,
    bf16* __restrict__ Wt2_lo, float* __restrict__ Vsum) {
  __shared__ float tile[64 * 65];
  const int mat = blockIdx.x >> 4;
  const int kb = blockIdx.x & 15;             // 64-k block -> rounds 2kb,2kb+1
  const int t = threadIdx.x;
  if (blockIdx.x == 0 && t < NBATCH * DDIM) Vsum[t] = 0.f;
  const float* W = (mat == 0) ? Wq : ((mat == 1) ? Wk : Wv);

#pragma unroll
  for (int i = 0; i < 4; i++) {
    int F = (i * 256 + t) * 4;                // flat f32 idx in [0,4096)
    int k = F >> 6;
    int n4 = F & 63;
    float4 v = *(const float4*)(const void*)(W + (size_t)(kb * 64 + k) * 64 + n4);
    tile[(n4 + 0) * 65 + k] = v.x;
    tile[(n4 + 1) * 65 + k] = v.y;
    tile[(n4 + 2) * 65 + k] = v.z;
    tile[(n4 + 3) * 65 + k] = v.w;
  }
  __syncthreads();

  // 512 units (hi+lo written together): nl, j_half, pp_k
#pragma unroll
  for (int it = 0; it < 2; it++) {
    int uidx = it * 256 + t;
    int nl = uidx >> 3;
    int j_half = (uidx >> 2) & 1;
    int pp_k = uidx & 3;
    int ng = mat * 64 + nl;                   // global n in [0,192)
    int n2 = ng >> 1;
    int sp = ((ng & 1) * 4 + pp_k) ^ (n2 & 7);
    int unit = n2 * 8 + sp;
    int j = kb * 2 + j_half;
    frag_u h, l;
#pragma unroll
    for (int e = 0; e < 8; e++) {
      float v = tile[nl * 65 + j_half * 32 + pp_k * 8 + e];
      bf16 hh = __float2bfloat16(v);
      h.e[e] = hh;
      l.e[e] = __float2bfloat16(v - __bfloat162float(hh));
    }
    size_t ob = (size_t)j * 6144 + unit * 8;
    *(bf16x8*)(void*)(Wt2_hi + ob) = h.v;
    *(bf16x8*)(void*)(Wt2_lo + ob) = l.v;
  }
}

// ---------------------------------------------------------------------------
// Fused QKV GEMM v8 — ALL-REGISTER pipeline (no LDS / barriers / DMA in the
// K-loop). v7 post-mortem: global_load_lds (HBM, ~900cy) shares the in-order
// vmcnt queue with B register loads issued after it, so B's 1-round slack
// inherited the DMA's latency every round (~2600 cyc/round observed).
// Now: A fragments are lane-local (row l16, k quad*8..+7 = 32 B/lane/round)
// -> load A straight to registers. Wave = 32 rows x 3 n-tiles, K-SPLIT:
// waves 0-3 (kh=0) do rounds 0-15, waves 4-7 (kh=1) rounds 16-31; one LDS
// accumulator exchange + single __syncthreads at the end merges halves.
// Grid 256 x 512 thr = 1 block/CU, 2 waves/SIMD. Per wave per round:
// 6 B loads (L2-hot packed Wt2, issued FIRST -> in-order retirement never
// blocks B behind slower A), 4 A loads (HBM, depth-3 / 4-slot ring ->
// ~3 rounds of slack > HBM latency), 2x cvt_split, 18 MFMA. Fully unrolled
// (16 rounds) so all buffer indices are compile-time -> registers.
// B L2 traffic: 768 KB/CU total (~5.7 us floor); x: 33.5 MB HBM once.
// MFMA f32_16x16x32_bf16 split-bf16 (xh*wh + xh*wl + xl*wh):
//   A[m][k]: m=lane&15, k=(lane>>4)*8+e | B[k][n]: n=lane&15, k=(lane>>4)*8+e
//   D[m][n]: m=(lane>>4)*4+r, n=lane&15
// ---------------------------------------------------------------------------
__global__ __launch_bounds__(512, 2) void qkv_gemm_kernel(
    const float* __restrict__ x, const bf16* __restrict__ Wt2_hi,
    const bf16* __restrict__ Wt2_lo, const float* __restrict__ bq,
    const float* __restrict__ bk, const float* __restrict__ bv,
    float* __restrict__ qkv, float* __restrict__ Vsum) {
  __shared__ f32x4 red[4][64][6];             // 24.5 KB, epilogue merge only
  const int tid = threadIdx.x;
  const int lane = tid & 63;
  const int wave = tid >> 6;                  // 0..7
  const int nh = wave & 3;                    // n-group (3 n-tiles)
  const int kh = wave >> 2;                   // k-half
  const int quad = lane >> 4;
  const int l16 = lane & 15;
  const int rowBase = blockIdx.x * 32;

  // B lane pointer (pre-swizzled pack layout; swizzle irrelevant for global
  // loads but kept so pack layout is shared): unit = nt*512 + loff bf16
  const int sp = ((l16 & 1) * 4 + quad) ^ ((l16 >> 1) & 7);
  const int loff = ((l16 >> 1) * 8 + sp) * 8;
  const bf16* bhp = Wt2_hi + (size_t)kh * 98304 + nh * 1536 + loff;  // 16*6144
  const bf16* blp = Wt2_lo + (size_t)kh * 98304 + nh * 1536 + loff;

  // A lane pointers: mfrag f row = rowBase + f*16 + l16, k-bytes = R*128 +
  // quad*32 (R = kh*16 + r folded into base)
  const char* aB0 = (const char*)x + (size_t)(rowBase + l16) * 4096 +
                    kh * 2048 + quad * 32;
  const char* aB1 = aB0 + 16 * 4096;

  float4 Ab[4][2][2];                         // [slot][mfrag][half]
  bf16x8 Bh[2][3], Bl[2][3];                  // [slot][t]
  f32x4 acc[2][3];
#pragma unroll
  for (int f = 0; f < 2; f++)
#pragma unroll
    for (int t = 0; t < 3; t++) acc[f][t] = (f32x4){0.f, 0.f, 0.f, 0.f};

#define LOADB(s, r)                                                          \
  {                                                                          \
    const bf16* _h = bhp + (r) * 6144;                                       \
    const bf16* _l = blp + (r) * 6144;                                       \
    Bh[s][0] = *(const bf16x8*)(const void*)(_h);                            \
    Bh[s][1] = *(const bf16x8*)(const void*)(_h + 512);                      \
    Bh[s][2] = *(const bf16x8*)(const void*)(_h + 1024);                     \
    Bl[s][0] = *(const bf16x8*)(const void*)(_l);                            \
    Bl[s][1] = *(const bf16x8*)(const void*)(_l + 512);                      \
    Bl[s][2] = *(const bf16x8*)(const void*)(_l + 1024);                     \
  }
#define LOADA(s, r)                                                          \
  {                                                                          \
    Ab[s][0][0] = *(const float4*)(const void*)(aB0 + (r) * 128);            \
    Ab[s][0][1] = *(const float4*)(const void*)(aB0 + (r) * 128 + 16);       \
    Ab[s][1][0] = *(const float4*)(const void*)(aB1 + (r) * 128);            \
    Ab[s][1][1] = *(const float4*)(const void*)(aB1 + (r) * 128 + 16);       \
  }

  // prologue: B round 0 first (in-order queue: B never behind HBM A loads)
  LOADB(0, 0);
  LOADA(0, 0);
  LOADA(1, 1);
  LOADA(2, 2);

#pragma unroll
  for (int r = 0; r < 16; ++r) {
    if (r + 1 < 16) LOADB((r + 1) & 1, r + 1);   // B first, slack 1 round
    if (r + 3 < 16) LOADA((r + 3) & 3, r + 3);   // A slack 3 rounds (HBM)
    bf16x8 ah0, al0, ah1, al1;
    cvt_split(Ab[r & 3][0][0], Ab[r & 3][0][1], ah0, al0);
    cvt_split(Ab[r & 3][1][0], Ab[r & 3][1][1], ah1, al1);
    const int s = r & 1;
#pragma unroll
    for (int t = 0; t < 3; t++) {
      acc[0][t] =
          __builtin_amdgcn_mfma_f32_16x16x32_bf16(ah0, Bh[s][t], acc[0][t], 0, 0, 0);
      acc[0][t] =
          __builtin_amdgcn_mfma_f32_16x16x32_bf16(ah0, Bl[s][t], acc[0][t], 0, 0, 0);
      acc[0][t] =
          __builtin_amdgcn_mfma_f32_16x16x32_bf16(al0, Bh[s][t], acc[0][t], 0, 0, 0);
      acc[1][t] =
          __builtin_amdgcn_mfma_f32_16x16x32_bf16(ah1, Bh[s][t], acc[1][t], 0, 0, 0);
      acc[1][t] =
          __builtin_amdgcn_mfma_f32_16x16x32_bf16(ah1, Bl[s][t], acc[1][t], 0, 0, 0);
      acc[1][t] =
          __builtin_amdgcn_mfma_f32_16x16x32_bf16(al1, Bh[s][t], acc[1][t], 0, 0, 0);
    }
  }
#undef LOADA
#undef LOADB

  // merge k-halves: waves 4-7 export, waves 0-3 absorb
  if (kh == 1) {
#pragma unroll
    for (int f = 0; f < 2; f++)
#pragma unroll
      for (int t = 0; t < 3; t++) red[nh][lane][f * 3 + t] = acc[f][t];
  }
  __syncthreads();
  if (kh == 1) return;
#pragma unroll
  for (int f = 0; f < 2; f++)
#pragma unroll
    for (int t = 0; t < 3; t++) acc[f][t] += red[nh][lane][f * 3 + t];

  // epilogue: bias + store + V column sums
  const int bb = rowBase >> 12;
#pragma unroll
  for (int f = 0; f < 2; f++)
#pragma unroll
    for (int t = 0; t < 3; t++) {
      int nt = nh * 3 + t;
      int n = nt * 16 + l16;
      int mat = n >> 6;
      int col = n & 63;
      float bias = (mat == 0) ? bq[col] : ((mat == 1) ? bk[col] : bv[col]);
      float* dst = qkv + (size_t)mat * MROWS * DDIM +
                   (size_t)(rowBase + f * 16 + quad * 4) * DDIM + col;
      float vs = 0.f;
#pragma unroll
      for (int rr = 0; rr < 4; rr++) {
        float val = acc[f][t][rr] + bias;
        dst[rr * DDIM] = val;
        vs += val;
      }
      if (nt >= 8) {                          // V tiles -> Vsum
        vs += __shfl_xor(vs, 16, 64);
        vs += __shfl_xor(vs, 32, 64);
        if (quad == 0) atomicAdd(&Vsum[bb * DDIM + (n - 128)], vs);
      }
    }
}

// ---------------------------------------------------------------------------
// Attention: 2 queries per wave, 32 lanes each, lane owns a float2 dim-pair.
// Full-row softmax collapses to: 5 window exps + (S - nvalid) background
// exp(0-m) terms; background numerator = Vsum - sum(window V).
// ---------------------------------------------------------------------------
__global__ __launch_bounds__(256) void attn_kernel(
    const float* __restrict__ qkv, const float* __restrict__ Vsum,
    float* __restrict__ out) {
  const float* Qf = qkv;
  const float* Kf = qkv + (size_t)MROWS * DDIM;
  const float* Vf = qkv + (size_t)2 * MROWS * DDIM;
  int l = threadIdx.x & 31;
  int qidx = blockIdx.x * 8 + (threadIdx.x >> 5);
  int b = qidx >> 12;
  int i = qidx & 4095;

  float2 q = *(const float2*)(const void*)(Qf + (size_t)qidx * DDIM + 2 * l);
  float sc[5];
  float2 vv[5];
  bool val[5];
#pragma unroll
  for (int w = 0; w < 5; w++) {
    int j = i + 2 * w - 4;                    // DIL*(w - WIN/2), DIL=2
    val[w] = (j >= 0) && (j < S_LEN);
    int jj = val[w] ? j : i;
    size_t off = (size_t)(b * S_LEN + jj) * DDIM + 2 * l;
    float2 kk = *(const float2*)(const void*)(Kf + off);
    vv[w] = *(const float2*)(const void*)(Vf + off);
    float p = q.x * kk.x + q.y * kk.y;
#pragma unroll
    for (int d = 1; d < 32; d <<= 1) p += __shfl_xor(p, d, 64);
    sc[w] = p;
  }

  float mx = 0.f;                             // background score 0 in the max
#pragma unroll
  for (int w = 0; w < 5; w++)
    if (val[w]) mx = fmaxf(mx, sc[w]);

  float denom = 0.f;
  float2 accv = {0.f, 0.f}, vsel = {0.f, 0.f};
  int nval = 0;
#pragma unroll
  for (int w = 0; w < 5; w++)
    if (val[w]) {
      float pexp = __expf(sc[w] - mx);
      denom += pexp;
      accv.x += pexp * vv[w].x;
      accv.y += pexp * vv[w].y;
      vsel.x += vv[w].x;
      vsel.y += vv[w].y;
      nval++;
    }
  float pbg = __expf(-mx);
  denom += pbg * (float)(S_LEN - nval);
  float2 vsm = *(const float2*)(const void*)(Vsum + b * DDIM + 2 * l);
  accv.x += pbg * (vsm.x - vsel.x);
  accv.y += pbg * (vsm.y - vsel.y);

  float2 o = {accv.x / denom, accv.y / denom};
  *(float2*)(void*)(out + (size_t)qidx * DDIM + 2 * l) = o;
}

// ---------------------------------------------------------------------------
extern "C" void kernel_launch(void* const* d_in, const int* in_sizes, int n_in,
                              void* d_out, int out_size, void* d_ws,
                              size_t ws_size, hipStream_t stream) {
  const float* x = (const float*)d_in[0];
  const float* Wq = (const float*)d_in[1];
  const float* bq = (const float*)d_in[2];
  const float* Wk = (const float*)d_in[3];
  const float* bk = (const float*)d_in[4];
  const float* Wv = (const float*)d_in[5];
  const float* bv = (const float*)d_in[6];
  float* out = (float*)d_out;

  char* ws = (char*)d_ws;
  bf16* Wt2_hi = (bf16*)ws;                   // 32*6144*2 = 393216 B
  bf16* Wt2_lo = (bf16*)(ws + 393216);        // 393216 B
  float* qkv = (float*)(ws + 786432);         // 3*8192*64*4 = 6291456 B
  float* Vsum = (float*)(ws + 786432 + 6291456);  // 512 B
  // total workspace ~7.1 MB

  hipLaunchKernelGGL(pack_w_kernel, dim3(48), dim3(256), 0, stream, Wq, Wk, Wv,
                     Wt2_hi, Wt2_lo, Vsum);
  hipLaunchKernelGGL(qkv_gemm_kernel, dim3(256), dim3(512), 0, stream, x,
                     Wt2_hi, Wt2_lo, bq, bk, bv, qkv, Vsum);
  hipLaunchKernelGGL(attn_kernel, dim3(1024), dim3(256), 0, stream, qkv, Vsum,
                     out);
}